// Round 1
// baseline (521.019 us; speedup 1.0000x reference)
//
#include <hip/hip_runtime.h>
#include <hip/hip_bf16.h>
#include <cstdint>
#include <cstddef>

// Problem constants (fixed by reference)
#define BB 4
#define CC 64
#define NN 4096
#define KK 20
#define NROW (BB*NN)       // 16384 rows total
#define CAP 384            // survivor cap per row
#define Q0f 27.0f          // analytic screen threshold on w = xx_m - 2*s  (d = xx_n + w)
#define QPf 27.005f        // push threshold (margin for fp32 vs fp64 discrepancy)

typedef float v2f __attribute__((ext_vector_type(2)));

__device__ __forceinline__ v2f pkfma(v2f a, v2f b, v2f c) {
  return __builtin_elementwise_fma(a, b, c);
}

// ---------------------------------------------------------------------------
// K1: prep. xT[b][n][c] (transposed points), xxf (f32 norms), xxd (f64 norms),
//           uT[b][n][o] = W1 . x[:,n], vT[b][n][o] = (W2-W1) . x[:,n]
// ---------------------------------------------------------------------------
__global__ __launch_bounds__(256) void k1_prep(
    const float* __restrict__ x, const float* __restrict__ W,
    float* __restrict__ xT, float* __restrict__ xxf, double* __restrict__ xxd,
    float* __restrict__ uT, float* __restrict__ vT)
{
  __shared__ float xl[64][65];   // [c][n], +1 pad (column reads)
  __shared__ float w1[64][65];   // [o][c]
  __shared__ float wd[64][65];   // [o][c] = W2-W1
  int t = threadIdx.x;
  int b  = blockIdx.x >> 6;
  int n0 = (blockIdx.x & 63) * 64;

  for (int i = t; i < 4096; i += 256) {
    int o = i >> 6, c = i & 63;
    float a = W[o*128 + c];
    w1[o][c] = a;
    wd[o][c] = W[o*128 + 64 + c] - a;
  }
  for (int i = t; i < 4096; i += 256) {
    int c = i >> 6, n = i & 63;
    xl[c][n] = x[((size_t)b*64 + c)*4096 + n0 + n];
  }
  __syncthreads();

  // transposed copy (coalesced writes)
  for (int i = t; i < 4096; i += 256) {
    int n = i >> 6, c = i & 63;
    xT[(((size_t)b*4096) + n0 + n)*64 + c] = xl[c][n];
  }
  // squared norms, f32 (4-acc tree) and f64
  if (t < 64) {
    int n = t;
    float s0=0,s1=0,s2=0,s3=0; double sd=0.0;
    for (int c = 0; c < 64; c += 4) {
      float a0=xl[c][n],a1=xl[c+1][n],a2=xl[c+2][n],a3=xl[c+3][n];
      s0=fmaf(a0,a0,s0); s1=fmaf(a1,a1,s1); s2=fmaf(a2,a2,s2); s3=fmaf(a3,a3,s3);
      sd += (double)a0*a0 + (double)a1*a1 + (double)a2*a2 + (double)a3*a3;
    }
    xxf[(size_t)b*4096 + n0 + n] = (s0+s1)+(s2+s3);
    xxd[(size_t)b*4096 + n0 + n] = sd;
  }
  __syncthreads();

  // u, v micro-GEMM; writes coalesced over o
  for (int i = t; i < 4096; i += 256) {
    int n = i >> 6, o = i & 63;
    float au = 0.f, av = 0.f;
    #pragma unroll 8
    for (int c = 0; c < 64; ++c) {
      float xv = xl[c][n];
      au = fmaf(w1[o][c], xv, au);
      av = fmaf(wd[o][c], xv, av);
    }
    size_t idx = (((size_t)b*4096) + n0 + n)*64 + o;
    uT[idx] = au;
    vT[idx] = av;
  }
}

// ---------------------------------------------------------------------------
// K2: fp32 Gram screen. wg = 256 thr = 4 waves, owns 64 rows x 1024 m (MSPLIT=4).
// wave-tile 16r x 64m, lane-tile 4r x 4m (16 acc). Pushes survivor keys
// (q<<12)|m (q = quantized w) via global atomics.
// ---------------------------------------------------------------------------
__global__ __launch_bounds__(256) void k2_screen(
    const float* __restrict__ x, const float* __restrict__ xxf,
    unsigned* __restrict__ counts, unsigned* __restrict__ strictc,
    unsigned* __restrict__ surv)
{
  __shared__ __align__(16) float xn[64][64];      // [c][n]
  __shared__ __align__(16) float xm[2][64][64];   // double-buffered [c][m]
  int t  = threadIdx.x;
  int rb = blockIdx.x >> 2;
  int ms = blockIdx.x & 3;
  int b  = rb >> 6;
  int n0 = (rb & 63) * 64;
  int m0 = ms * 1024;
  const float* xb = x + (size_t)b*64*4096;

  int c0 = t >> 4, nq = (t & 15) * 4;
  // stage xn and chunk 0 of xm
  #pragma unroll
  for (int rdd = 0; rdd < 4; ++rdd) {
    int c = c0 + rdd*16;
    *(float4*)&xn[c][nq]    = *(const float4*)(xb + (size_t)c*4096 + n0 + nq);
    *(float4*)&xm[0][c][nq] = *(const float4*)(xb + (size_t)c*4096 + m0 + nq);
  }
  __syncthreads();

  int wv = t >> 6, lane = t & 63;
  int i4 = ((lane >> 4) & 3) * 4;   // row sub-offset
  int j4 = (lane & 15) * 4;         // m sub-offset
  int wb = wv * 16;
  int rowg[4];
  #pragma unroll
  for (int r = 0; r < 4; ++r) rowg[r] = b*4096 + n0 + wb + i4 + r;

  for (int ch = 0; ch < 16; ++ch) {
    int cur = ch & 1;
    // issue next-chunk global loads early (hide HBM/L2 latency under compute)
    float4 stg0, stg1, stg2, stg3;
    if (ch < 15) {
      const float* src = xb + (size_t)0 + m0 + (ch+1)*64 + nq;
      stg0 = *(const float4*)(src + (size_t)(c0 +  0)*4096);
      stg1 = *(const float4*)(src + (size_t)(c0 + 16)*4096);
      stg2 = *(const float4*)(src + (size_t)(c0 + 32)*4096);
      stg3 = *(const float4*)(src + (size_t)(c0 + 48)*4096);
    }
    // 16 fp32 dot accumulators (as 8 packed f32x2)
    v2f acc[4][2];
    #pragma unroll
    for (int r = 0; r < 4; ++r) { acc[r][0].x=0.f; acc[r][0].y=0.f; acc[r][1].x=0.f; acc[r][1].y=0.f; }
    #pragma unroll 8
    for (int c = 0; c < 64; ++c) {
      float4 xnv = *(const float4*)&xn[c][wb + i4];
      float4 xmv = *(const float4*)&xm[cur][c][j4];
      v2f m01; m01.x = xmv.x; m01.y = xmv.y;
      v2f m23; m23.x = xmv.z; m23.y = xmv.w;
      #pragma unroll
      for (int r = 0; r < 4; ++r) {
        float xr = (r==0)?xnv.x:(r==1)?xnv.y:(r==2)?xnv.z:xnv.w;
        v2f xs; xs.x = xr; xs.y = xr;
        acc[r][0] = pkfma(xs, m01, acc[r][0]);
        acc[r][1] = pkfma(xs, m23, acc[r][1]);
      }
    }
    // screen epilogue: w = xx_m - 2*s ; push if below threshold
    float4 xxm = *(const float4*)(xxf + (size_t)b*4096 + m0 + ch*64 + j4);
    #pragma unroll
    for (int r = 0; r < 4; ++r) {
      #pragma unroll
      for (int mm = 0; mm < 4; ++mm) {
        float a = (mm==0)?acc[r][0].x:(mm==1)?acc[r][0].y:(mm==2)?acc[r][1].x:acc[r][1].y;
        float xxv = (mm==0)?xxm.x:(mm==1)?xxm.y:(mm==2)?xxm.z:xxm.w;
        float w = fmaf(-2.0f, a, xxv);
        if (w < QPf) {
          int mg = m0 + ch*64 + j4 + mm;
          int qi = (int)((w + 69.0f) * 512.0f);
          qi = min(max(qi, 0), 65535);
          unsigned key = ((unsigned)qi << 12) | (unsigned)(mg & 4095);
          unsigned slot = atomicAdd(&counts[rowg[r]], 1u);
          if (slot < CAP) surv[(size_t)rowg[r]*CAP + slot] = key;
          if (w < Q0f) atomicAdd(&strictc[rowg[r]], 1u);
        }
      }
    }
    // write staged chunk, one barrier per chunk
    if (ch < 15) {
      int nxt = cur ^ 1;
      *(float4*)&xm[nxt][c0 +  0][nq] = stg0;
      *(float4*)&xm[nxt][c0 + 16][nq] = stg1;
      *(float4*)&xm[nxt][c0 + 32][nq] = stg2;
      *(float4*)&xm[nxt][c0 + 48][nq] = stg3;
    }
    __syncthreads();
  }
}

// ---------------------------------------------------------------------------
// shared epilogue: given the row's 20 neighbor indices, gather u, compute
// per-(o) max / sum / sumsq, stage max+v, accumulate global f64 sums.
// ---------------------------------------------------------------------------
template <typename F>
__device__ __forceinline__ void row_epilogue(
    F getm, const float* __restrict__ uT, const float* __restrict__ vT,
    float* __restrict__ stage, double* __restrict__ S1, double* __restrict__ S2,
    int b, int n, int lane)
{
  const float* ub = uT + (size_t)b*4096*64;
  float mx = -3.4e38f, s1 = 0.f, s2 = 0.f;
  #pragma unroll
  for (int k = 0; k < 20; ++k) {
    unsigned m = getm(k);
    float g = ub[(size_t)m*64 + lane];
    mx = fmaxf(mx, g); s1 += g; s2 = fmaf(g, g, s2);
  }
  size_t ro = ((size_t)b*4096 + n)*64 + lane;
  float v = vT[ro];
  stage[ro] = mx + v;
  double dv = (double)v;
  __hip_atomic_fetch_add(&S1[b*64 + lane], (double)s1 + 20.0*dv,
                         __ATOMIC_RELAXED, __HIP_MEMORY_SCOPE_AGENT);
  __hip_atomic_fetch_add(&S2[b*64 + lane], (double)s2 + 2.0*dv*(double)s1 + 20.0*dv*dv,
                         __ATOMIC_RELAXED, __HIP_MEMORY_SCOPE_AGENT);
}

// ---------------------------------------------------------------------------
// K3: per-row (one wave per row): bisect top-26 survivor keys, f64 rescore,
// bitonic sort -> exact top-20, then epilogue. Flags pathological rows.
// ---------------------------------------------------------------------------
__global__ __launch_bounds__(256) void k3_select(
    const float* __restrict__ xT, const double* __restrict__ xxd,
    const unsigned* __restrict__ counts, const unsigned* __restrict__ strictc,
    const unsigned* __restrict__ surv,
    const float* __restrict__ uT, const float* __restrict__ vT,
    float* __restrict__ stage, double* __restrict__ S1, double* __restrict__ S2,
    unsigned* __restrict__ slowcnt, unsigned* __restrict__ slowlist)
{
  __shared__ unsigned candm[4][32];
  int wv = threadIdx.x >> 6, lane = threadIdx.x & 63;
  int row = blockIdx.x * 4 + wv;
  int b = row >> 12, n = row & 4095;

  unsigned rawcnt = counts[row];
  unsigned st     = strictc[row];
  if (st < 20u || rawcnt > (unsigned)CAP) {          // safety slow-path
    if (lane == 0) { unsigned i = atomicAdd(slowcnt, 1u); slowlist[i] = row; }
    return;
  }
  int cnt = (int)rawcnt;

  unsigned key[6];
  #pragma unroll
  for (int s = 0; s < 6; ++s) {
    int i = lane + s*64;
    key[s] = (i < cnt) ? surv[(size_t)row*CAP + i] : 0xFFFFFFFFu;
  }
  int target = min(cnt, 26);
  // bisection on 28-bit key space -> exact set of 'target' smallest keys
  unsigned lo = 0u, hi = 1u << 28;
  for (int it = 0; it < 28; ++it) {
    unsigned mid = (lo + hi) >> 1;
    int c = 0;
    #pragma unroll
    for (int s = 0; s < 6; ++s)
      c += __popcll(__ballot(key[s] < mid));
    if (c >= target) hi = mid; else lo = mid;
  }
  // compact winners into LDS
  int base = 0;
  #pragma unroll
  for (int s = 0; s < 6; ++s) {
    unsigned long long mask = __ballot(key[s] < hi);
    if (key[s] < hi) {
      int pos = base + __popcll(mask & ((1ull << lane) - 1ull));
      candm[wv][pos] = key[s] & 0xFFFu;
    }
    base += __popcll(mask);
  }
  __builtin_amdgcn_wave_barrier();

  // exact f64 rescore of <=26 candidates
  unsigned long long k64 = ~0ull;
  if (lane < target) {
    int m = (int)candm[wv][lane];
    const float* pn = xT + ((size_t)b*4096 + n)*64;
    const float* pm = xT + ((size_t)b*4096 + m)*64;
    double acc = 0.0;
    #pragma unroll 4
    for (int c = 0; c < 64; c += 4) {
      float4 a  = *(const float4*)(pn + c);
      float4 bf = *(const float4*)(pm + c);
      acc = fma((double)a.x, (double)bf.x, acc);
      acc = fma((double)a.y, (double)bf.y, acc);
      acc = fma((double)a.z, (double)bf.z, acc);
      acc = fma((double)a.w, (double)bf.w, acc);
    }
    double d = xxd[(size_t)b*4096 + n] + xxd[(size_t)b*4096 + m] - 2.0*acc;
    d = fmax(d, 0.0);
    // pack index into low 12 mantissa bits: ties -> lower index, matches top_k
    k64 = (((unsigned long long)__double_as_longlong(d)) & ~0xFFFull)
        | (unsigned long long)m;
  }
  // bitonic sort across 64 lanes (ascending)
  #pragma unroll
  for (int kk = 2; kk <= 64; kk <<= 1) {
    #pragma unroll
    for (int j = kk >> 1; j > 0; j >>= 1) {
      unsigned long long o = __shfl_xor(k64, j);
      bool up    = ((lane & kk) == 0);
      bool lower = ((lane & j) == 0);
      unsigned long long mn = (k64 < o) ? k64 : o;
      unsigned long long mx = (k64 < o) ? o : k64;
      k64 = (lower == up) ? mn : mx;
    }
  }
  int mlow = (int)(k64 & 0xFFFull);   // lanes 0..19 hold the top-20
  row_epilogue([&](int k) { return (unsigned)__shfl(mlow, k); },
               uT, vT, stage, S1, S2, b, n, lane);
}

// ---------------------------------------------------------------------------
// K3b: slow path for flagged rows (expected ~0): full f64 scan + extraction.
// ---------------------------------------------------------------------------
__global__ __launch_bounds__(256) void k3b_slow(
    const float* __restrict__ xT, const double* __restrict__ xxd,
    const unsigned* __restrict__ slowcnt, const unsigned* __restrict__ slowlist,
    const float* __restrict__ uT, const float* __restrict__ vT,
    float* __restrict__ stage, double* __restrict__ S1, double* __restrict__ S2)
{
  __shared__ unsigned long long keyl[4096];
  __shared__ unsigned long long red[4];
  __shared__ unsigned t20[20];
  unsigned nslow = *slowcnt;
  int t = threadIdx.x;
  for (unsigned ii = blockIdx.x; ii < nslow; ii += gridDim.x) {
    int row = (int)slowlist[ii];
    int b = row >> 12, n = row & 4095;
    const float* pn = xT + ((size_t)b*4096 + n)*64;
    double xxn = xxd[(size_t)b*4096 + n];
    for (int m = t; m < 4096; m += 256) {
      const float* pm = xT + ((size_t)b*4096 + m)*64;
      double acc = 0.0;
      #pragma unroll 4
      for (int c = 0; c < 64; c += 4) {
        float4 a  = *(const float4*)(pn + c);
        float4 bf = *(const float4*)(pm + c);
        acc = fma((double)a.x, (double)bf.x, acc);
        acc = fma((double)a.y, (double)bf.y, acc);
        acc = fma((double)a.z, (double)bf.z, acc);
        acc = fma((double)a.w, (double)bf.w, acc);
      }
      double d = fmax(xxn + xxd[(size_t)b*4096 + m] - 2.0*acc, 0.0);
      keyl[m] = (((unsigned long long)__double_as_longlong(d)) & ~0xFFFull)
              | (unsigned long long)m;
    }
    __syncthreads();
    for (int k = 0; k < 20; ++k) {
      unsigned long long mn = ~0ull;
      #pragma unroll
      for (int s = 0; s < 16; ++s) {
        unsigned long long v = keyl[t + s*256];
        mn = (v < mn) ? v : mn;
      }
      for (int off = 32; off > 0; off >>= 1) {
        unsigned long long o = __shfl_down(mn, off);
        mn = (o < mn) ? o : mn;
      }
      if ((t & 63) == 0) red[t >> 6] = mn;
      __syncthreads();
      if (t == 0) {
        unsigned long long w0 = red[0];
        for (int q = 1; q < 4; ++q) w0 = (red[q] < w0) ? red[q] : w0;
        t20[k] = (unsigned)(w0 & 0xFFFull);
        keyl[w0 & 0xFFFull] = ~0ull;
      }
      __syncthreads();
    }
    if (t < 64) {
      row_epilogue([&](int k) { return t20[k]; },
                   uT, vT, stage, S1, S2, b, n, t);
    }
    __syncthreads();
  }
}

// ---------------------------------------------------------------------------
// K4: finalize. mean/var per (b,o), normalize staged max, leaky-ReLU, write.
// ---------------------------------------------------------------------------
__global__ __launch_bounds__(256) void k4_final(
    const float* __restrict__ stage, const double* __restrict__ S1,
    const double* __restrict__ S2, float* __restrict__ out)
{
  int bo = blockIdx.x;                 // b*64 + o
  double inv = 1.0 / (4096.0 * 20.0);
  double mean = S1[bo] * inv;
  double var  = S2[bo] * inv - mean * mean;
  float rs = (float)rsqrt(var + 1e-5);
  float mf = (float)mean;
  int b = bo >> 6, o = bo & 63;
  for (int n = threadIdx.x; n < 4096; n += 256) {
    float y = (stage[((size_t)b*4096 + n)*64 + o] - mf) * rs;
    out[(size_t)bo*4096 + n] = (y >= 0.f) ? y : 0.2f * y;
  }
}

// ---------------------------------------------------------------------------
extern "C" void kernel_launch(void* const* d_in, const int* in_sizes, int n_in,
                              void* d_out, int out_size, void* d_ws, size_t ws_size,
                              hipStream_t stream)
{
  (void)in_sizes; (void)n_in; (void)out_size; (void)ws_size;
  const float* x = (const float*)d_in[0];   // (4,64,4096)
  const float* W = (const float*)d_in[1];   // (64,128)
  float* out = (float*)d_out;

  char* ws = (char*)d_ws;
  size_t off = 0;
  auto alloc = [&](size_t bytes) {
    char* p = ws + off;
    off = (off + bytes + 255) & ~(size_t)255;
    return p;
  };
  float*    uT       = (float*)   alloc((size_t)BB*NN*64*4);
  float*    vT       = (float*)   alloc((size_t)BB*NN*64*4);
  float*    xT       = (float*)   alloc((size_t)BB*NN*64*4);
  float*    stage    = (float*)   alloc((size_t)BB*NN*64*4);
  float*    xxf      = (float*)   alloc((size_t)NROW*4);
  double*   xxd      = (double*)  alloc((size_t)NROW*8);
  unsigned* counts   = (unsigned*)alloc((size_t)NROW*4);
  unsigned* strictc  = (unsigned*)alloc((size_t)NROW*4);
  double*   S1       = (double*)  alloc(256*8);
  double*   S2       = (double*)  alloc(256*8);
  unsigned* slowcnt  = (unsigned*)alloc(256);
  unsigned* slowlist = (unsigned*)alloc((size_t)NROW*4);
  unsigned* surv     = (unsigned*)alloc((size_t)NROW*CAP*4);

  // zero counters/accumulators (counts..slowcnt are contiguous by construction)
  size_t zbytes = (size_t)NROW*4 + (size_t)NROW*4 + 256*8 + 256*8 + 256;
  hipMemsetAsync(counts, 0, zbytes, stream);

  k1_prep  <<<256,  256, 0, stream>>>(x, W, xT, xxf, xxd, uT, vT);
  k2_screen<<<1024, 256, 0, stream>>>(x, xxf, counts, strictc, surv);
  k3_select<<<4096, 256, 0, stream>>>(xT, xxd, counts, strictc, surv,
                                      uT, vT, stage, S1, S2, slowcnt, slowlist);
  k3b_slow <<<64,   256, 0, stream>>>(xT, xxd, slowcnt, slowlist,
                                      uT, vT, stage, S1, S2);
  k4_final <<<256,  256, 0, stream>>>(stage, S1, S2, out);
}

// Round 2
// 330.098 us; speedup vs baseline: 1.5784x; 1.5784x over previous
//
#include <hip/hip_runtime.h>
#include <hip/hip_bf16.h>
#include <cstdint>
#include <cstddef>

// Problem constants (fixed by reference)
#define BB 4
#define NN 4096
#define NROW (BB*NN)          // 16384 rows
#define CAP 384               // survivor cap per row
#define QPf 27.7f             // push threshold on w_approx (27 + 2*eps, eps<=0.30)
#define STRICT_KEY (49152u<<12)  // quantized key for w_approx < 27.0  ((27+69)*512)
#define DQ 386u               // selection window in q units (> 2*eps*512 + 2)

typedef float v2f   __attribute__((ext_vector_type(2)));
typedef float f32x16 __attribute__((ext_vector_type(16)));
typedef short s16x8 __attribute__((ext_vector_type(8)));
typedef __bf16 bf16x8 __attribute__((ext_vector_type(8)));

__device__ __forceinline__ v2f pkfma(v2f a, v2f b, v2f c) {
  return __builtin_elementwise_fma(a, b, c);
}
__device__ __forceinline__ unsigned short f2bf(float f) {
  unsigned u = __float_as_uint(f);
  u += 0x7FFFu + ((u >> 16) & 1u);      // round-to-nearest-even (no NaN/Inf in data)
  return (unsigned short)(u >> 16);
}
__device__ __forceinline__ float bf2f(unsigned short h) {
  return __uint_as_float(((unsigned)h) << 16);
}

// ---------------------------------------------------------------------------
// K1: prep. xT f32 [point][c]; xh/xl bf16 hi/lo split [point][c]; xxf/xxd norms;
//     uT = W1.x, vT = (W2-W1).x  [point][o]  (weights held in registers)
// ---------------------------------------------------------------------------
__global__ __launch_bounds__(256) void k1_prep(
    const float* __restrict__ x, const float* __restrict__ W,
    float* __restrict__ xT, unsigned short* __restrict__ xh, unsigned short* __restrict__ xl,
    float* __restrict__ xxf, double* __restrict__ xxd,
    float* __restrict__ uT, float* __restrict__ vT)
{
  __shared__ float xc[64][65];   // [c][n]
  __shared__ float xr[64][68];   // [n][c], row stride 272B (16B aligned)
  __shared__ float w1[64][65];
  __shared__ float wd[64][65];
  int t = threadIdx.x;
  int b  = blockIdx.x >> 6;
  int n0 = (blockIdx.x & 63) * 64;

  for (int i = t; i < 4096; i += 256) {
    int o = i >> 6, c = i & 63;
    float a = W[o*128 + c];
    w1[o][c] = a;
    wd[o][c] = W[o*128 + 64 + c] - a;
  }
  for (int i = t; i < 4096; i += 256) {
    int c = i >> 6, n = i & 63;
    xc[c][n] = x[((size_t)b*64 + c)*4096 + n0 + n];
  }
  __syncthreads();

  // transposed copies + bf16 hi/lo split (coalesced over c)
  for (int i = t; i < 4096; i += 256) {
    int n = i >> 6, c = i & 63;          // n wave-uniform, c = lane
    float v = xc[c][n];
    xr[n][c] = v;
    size_t pi = ((size_t)b*4096 + n0 + n)*64 + c;
    xT[pi] = v;
    unsigned short h = f2bf(v);
    float l = v - bf2f(h);
    xh[pi] = h;
    xl[pi] = f2bf(l);
  }
  // squared norms (f32 + f64)
  if (t < 64) {
    int n = t;
    float s0=0,s1=0,s2=0,s3=0; double sd=0.0;
    for (int c = 0; c < 64; c += 4) {
      float a0=xc[c][n],a1=xc[c+1][n],a2=xc[c+2][n],a3=xc[c+3][n];
      s0=fmaf(a0,a0,s0); s1=fmaf(a1,a1,s1); s2=fmaf(a2,a2,s2); s3=fmaf(a3,a3,s3);
      sd += (double)a0*a0 + (double)a1*a1 + (double)a2*a2 + (double)a3*a3;
    }
    xxf[(size_t)b*4096 + n0 + n] = (s0+s1)+(s2+s3);
    xxd[(size_t)b*4096 + n0 + n] = sd;
  }
  // weights into registers (o = lane); conflict-free (pad 65)
  v2f w1r[32], wdr[32];
  int o = t & 63;
  #pragma unroll
  for (int j = 0; j < 32; ++j) {
    w1r[j].x = w1[o][2*j]; w1r[j].y = w1[o][2*j+1];
    wdr[j].x = wd[o][2*j]; wdr[j].y = wd[o][2*j+1];
  }
  __syncthreads();

  // u,v micro-GEMM: broadcast b128 x-reads, register weights
  for (int i = t; i < 4096; i += 256) {
    int n = i >> 6;                      // wave-uniform
    v2f au; au.x=0.f; au.y=0.f;
    v2f av; av.x=0.f; av.y=0.f;
    #pragma unroll
    for (int cb = 0; cb < 16; ++cb) {
      float4 xv = *(const float4*)&xr[n][cb*4];
      v2f p0; p0.x = xv.x; p0.y = xv.y;
      v2f p1; p1.x = xv.z; p1.y = xv.w;
      au = pkfma(w1r[2*cb],   p0, au);
      au = pkfma(w1r[2*cb+1], p1, au);
      av = pkfma(wdr[2*cb],   p0, av);
      av = pkfma(wdr[2*cb+1], p1, av);
    }
    size_t idx = ((size_t)b*4096 + n0 + n)*64 + o;
    uT[idx] = au.x + au.y;
    vT[idx] = av.x + av.y;
  }
}

// ---------------------------------------------------------------------------
// K2: split-bf16 MFMA Gram screen. Grid = 64 n-blocks x 8 m-splits.
// Block: 256 rows, 4 waves x 64 rows; sweeps 512 m in 4 chunks of 128.
// S = h.h + h.l + l.h via mfma_f32_32x32x16_bf16 (|err| <= 0.14 on S).
// ---------------------------------------------------------------------------
__global__ __launch_bounds__(256) void k2_screen(
    const unsigned short* __restrict__ xh, const unsigned short* __restrict__ xl,
    const float* __restrict__ xxf,
    unsigned* __restrict__ counts, unsigned* __restrict__ surv)
{
  __shared__ unsigned short mh[2][8192];   // [buf][128 m][64 c], XOR-swizzled
  __shared__ unsigned short ml[2][8192];
  int t  = threadIdx.x;
  int nb = blockIdx.x >> 3;
  int ms = blockIdx.x & 7;
  int row0 = nb * 256;                     // global point row base
  int b = row0 >> 12;
  int mbase = ms * 512;                    // local m base within batch
  const unsigned short* xhB = xh + ((size_t)b*4096)*64;
  const unsigned short* xlB = xl + ((size_t)b*4096)*64;

  int wv = t >> 6, lane = t & 63;
  int lr = lane & 31, oct = lane >> 5;

  // A-fragments in registers: 64 rows/wave = 2 ntiles x 32; row = lane&31,
  // k-octet = lane>>5, 8 contiguous c per frag (k-order cancels: A,B fed identically)
  s16x8 ah[2][4], al[2][4];
  #pragma unroll
  for (int nt = 0; nt < 2; ++nt)
    #pragma unroll
    for (int ks = 0; ks < 4; ++ks) {
      size_t rbase = ((size_t)(row0 + wv*64 + nt*32 + lr))*64 + ks*16 + oct*8;
      ah[nt][ks] = *(const s16x8*)(xh + rbase);
      al[nt][ks] = *(const s16x8*)(xl + rbase);
    }

  // stage chunk 0 (LDS write side swizzled: byte ^= ((m&7)<<4))
  {
    const char* sH = (const char*)(xhB + (size_t)mbase*64);
    const char* sL = (const char*)(xlB + (size_t)mbase*64);
    #pragma unroll
    for (int it = 0; it < 4; ++it) {
      int j  = it*4096 + t*16;
      int js = j ^ (((j >> 7) & 7) << 4);
      *(float4*)((char*)&mh[0][0] + js) = *(const float4*)(sH + j);
      *(float4*)((char*)&ml[0][0] + js) = *(const float4*)(sL + j);
    }
  }
  __syncthreads();

  for (int ch = 0; ch < 4; ++ch) {
    int cur = ch & 1;
    // prefetch next chunk into registers (hidden under MFMA)
    float4 pH[4], pL[4];
    if (ch < 3) {
      const char* sH = (const char*)(xhB + (size_t)(mbase + (ch+1)*128)*64);
      const char* sL = (const char*)(xlB + (size_t)(mbase + (ch+1)*128)*64);
      #pragma unroll
      for (int it = 0; it < 4; ++it) {
        int j = it*4096 + t*16;
        pH[it] = *(const float4*)(sH + j);
        pL[it] = *(const float4*)(sL + j);
      }
    }
    #pragma unroll
    for (int msub = 0; msub < 4; ++msub) {
      s16x8 bhf[4], blf[4];
      int mloc = msub*32 + lr;
      #pragma unroll
      for (int ks = 0; ks < 4; ++ks) {
        int off  = mloc*128 + ks*32 + oct*16;
        int offs = off ^ ((mloc & 7) << 4);
        bhf[ks] = *(const s16x8*)((const char*)&mh[cur][0] + offs);
        blf[ks] = *(const s16x8*)((const char*)&ml[cur][0] + offs);
      }
      f32x16 a0, a1;
      #pragma unroll
      for (int i = 0; i < 16; ++i) { a0[i] = 0.f; a1[i] = 0.f; }
      #pragma unroll
      for (int ks = 0; ks < 4; ++ks) {
        bf16x8 AH0 = __builtin_bit_cast(bf16x8, ah[0][ks]);
        bf16x8 AH1 = __builtin_bit_cast(bf16x8, ah[1][ks]);
        bf16x8 AL0 = __builtin_bit_cast(bf16x8, al[0][ks]);
        bf16x8 AL1 = __builtin_bit_cast(bf16x8, al[1][ks]);
        bf16x8 BH  = __builtin_bit_cast(bf16x8, bhf[ks]);
        bf16x8 BL  = __builtin_bit_cast(bf16x8, blf[ks]);
        a0 = __builtin_amdgcn_mfma_f32_32x32x16_bf16(AH0, BH, a0, 0, 0, 0);
        a1 = __builtin_amdgcn_mfma_f32_32x32x16_bf16(AH1, BH, a1, 0, 0, 0);
        a0 = __builtin_amdgcn_mfma_f32_32x32x16_bf16(AH0, BL, a0, 0, 0, 0);
        a1 = __builtin_amdgcn_mfma_f32_32x32x16_bf16(AH1, BL, a1, 0, 0, 0);
        a0 = __builtin_amdgcn_mfma_f32_32x32x16_bf16(AL0, BH, a0, 0, 0, 0);
        a1 = __builtin_amdgcn_mfma_f32_32x32x16_bf16(AL1, BH, a1, 0, 0, 0);
      }
      // epilogue: w = xx_m - 2*S; push survivors
      int mg = mbase + ch*128 + msub*32 + lr;        // local m in [0,4096)
      float xxm = xxf[b*4096 + mg];
      #pragma unroll
      for (int i = 0; i < 16; ++i) {
        int rsub = (i & 3) + 8*(i >> 2) + 4*oct;     // C/D row map (measured)
        float w0 = fmaf(-2.0f, a0[i], xxm);
        if (w0 < QPf) {
          int row = row0 + wv*64 + rsub;
          int qi = (int)((w0 + 69.0f) * 512.0f);
          qi = min(max(qi, 0), 65535);
          unsigned key = ((unsigned)qi << 12) | (unsigned)mg;
          unsigned slot = atomicAdd(&counts[row], 1u);
          if (slot < CAP) surv[(size_t)row*CAP + slot] = key;
        }
        float w1v = fmaf(-2.0f, a1[i], xxm);
        if (w1v < QPf) {
          int row = row0 + wv*64 + 32 + rsub;
          int qi = (int)((w1v + 69.0f) * 512.0f);
          qi = min(max(qi, 0), 65535);
          unsigned key = ((unsigned)qi << 12) | (unsigned)mg;
          unsigned slot = atomicAdd(&counts[row], 1u);
          if (slot < CAP) surv[(size_t)row*CAP + slot] = key;
        }
      }
    }
    if (ch < 3) {
      __syncthreads();
      int nxt = cur ^ 1;
      #pragma unroll
      for (int it = 0; it < 4; ++it) {
        int j  = it*4096 + t*16;
        int js = j ^ (((j >> 7) & 7) << 4);
        *(float4*)((char*)&mh[nxt][0] + js) = pH[it];
        *(float4*)((char*)&ml[nxt][0] + js) = pL[it];
      }
      __syncthreads();
    }
  }
}

// ---------------------------------------------------------------------------
// K3: per-row wave. strict-count + 20th-key bisection from quantized keys;
// select all keys within DQ window (guaranteed superset of true top-20);
// f64 rescore; bitonic sort; gather/max epilogue. Partial sums -> pS1/pS2.
// ---------------------------------------------------------------------------
__global__ __launch_bounds__(256) void k3_select(
    const float* __restrict__ xT, const double* __restrict__ xxd,
    const unsigned* __restrict__ counts, const unsigned* __restrict__ surv,
    const float* __restrict__ uT, const float* __restrict__ vT,
    float* __restrict__ stage, double* __restrict__ pS1, double* __restrict__ pS2,
    unsigned* __restrict__ slowcnt, unsigned* __restrict__ slowlist)
{
  __shared__ unsigned candm[4][64];
  __shared__ double ps1[4][64], ps2[4][64];
  int wv = threadIdx.x >> 6, lane = threadIdx.x & 63;
  int row = blockIdx.x * 4 + wv;
  int b = row >> 12, n = row & 4095;

  double s1t = 0.0, s2t = 0.0;
  unsigned rawcnt = counts[row];
  bool slow = (rawcnt > (unsigned)CAP);
  int cnt = slow ? 0 : (int)rawcnt;

  unsigned key[6];
  #pragma unroll
  for (int s = 0; s < 6; ++s) {
    int i = lane + s*64;
    key[s] = (i < cnt) ? surv[(size_t)row*CAP + i] : 0xFFFFFFFFu;
  }
  // strict count (w_approx < 27) derived from keys — no extra atomics
  int strictc = 0;
  #pragma unroll
  for (int s = 0; s < 6; ++s)
    strictc += __popcll(__ballot(key[s] < STRICT_KEY));
  slow = slow || (strictc < 20);

  int sel = 0;
  if (!slow) {
    // bisection: exact 20th-smallest key
    unsigned lo = 0u, hi = 1u << 28;
    for (int it = 0; it < 28; ++it) {
      unsigned mid = (lo + hi) >> 1;
      int c = 0;
      #pragma unroll
      for (int s = 0; s < 6; ++s)
        c += __popcll(__ballot(key[s] < mid));
      if (c >= 20) hi = mid; else lo = mid;
    }
    unsigned T = ((lo >> 12) + DQ) << 12;   // q20 + window
    int c = 0;
    #pragma unroll
    for (int s = 0; s < 6; ++s)
      c += __popcll(__ballot(key[s] < T));
    sel = c;
    if (sel > 64) {
      slow = true;
    } else {
      int base = 0;
      #pragma unroll
      for (int s = 0; s < 6; ++s) {
        unsigned long long mask = __ballot(key[s] < T);
        if (key[s] < T) {
          int pos = base + __popcll(mask & ((1ull << lane) - 1ull));
          candm[wv][pos] = key[s] & 0xFFFu;
        }
        base += __popcll(mask);
      }
    }
  }

  if (!slow) {
    __builtin_amdgcn_wave_barrier();
    // exact f64 rescore (<=64 candidates, one per lane)
    unsigned long long k64 = ~0ull;
    if (lane < sel) {
      int m = (int)candm[wv][lane];
      const float* pn = xT + ((size_t)b*4096 + n)*64;
      const float* pm = xT + ((size_t)b*4096 + m)*64;
      double acc = 0.0;
      #pragma unroll 4
      for (int c2 = 0; c2 < 64; c2 += 4) {
        float4 a  = *(const float4*)(pn + c2);
        float4 bf = *(const float4*)(pm + c2);
        acc = fma((double)a.x, (double)bf.x, acc);
        acc = fma((double)a.y, (double)bf.y, acc);
        acc = fma((double)a.z, (double)bf.z, acc);
        acc = fma((double)a.w, (double)bf.w, acc);
      }
      double d = xxd[(size_t)b*4096 + n] + xxd[(size_t)b*4096 + m] - 2.0*acc;
      d = fmax(d, 0.0);
      k64 = (((unsigned long long)__double_as_longlong(d)) & ~0xFFFull)
          | (unsigned long long)m;            // tie -> lower index (lax.top_k)
    }
    // 64-lane bitonic sort ascending
    #pragma unroll
    for (int kk = 2; kk <= 64; kk <<= 1) {
      #pragma unroll
      for (int j = kk >> 1; j > 0; j >>= 1) {
        unsigned long long o = __shfl_xor(k64, j);
        bool up    = ((lane & kk) == 0);
        bool lower = ((lane & j) == 0);
        unsigned long long mn = (k64 < o) ? k64 : o;
        unsigned long long mx = (k64 < o) ? o : k64;
        k64 = (lower == up) ? mn : mx;
      }
    }
    int mlow = (int)(k64 & 0xFFFull);          // lanes 0..19 = top-20
    // gather + max + sums (lane = o)
    const float* ub = uT + (size_t)b*4096*64;
    float mx = -3.4e38f, s1 = 0.f, s2 = 0.f;
    #pragma unroll
    for (int k = 0; k < 20; ++k) {
      int m = __shfl(mlow, k);
      float g = ub[(size_t)m*64 + lane];
      mx = fmaxf(mx, g); s1 += g; s2 = fmaf(g, g, s2);
    }
    size_t ro = ((size_t)b*4096 + n)*64 + lane;
    float v = vT[ro];
    stage[ro] = mx + v;
    double dv = (double)v;
    s1t = (double)s1 + 20.0*dv;
    s2t = (double)s2 + 2.0*dv*(double)s1 + 20.0*dv*dv;
  } else {
    if (lane == 0) { unsigned i = atomicAdd(slowcnt, 1u); slowlist[i] = row; }
  }

  ps1[wv][lane] = s1t; ps2[wv][lane] = s2t;
  __syncthreads();
  if (wv == 0) {
    pS1[(size_t)blockIdx.x*64 + lane] = ps1[0][lane]+ps1[1][lane]+ps1[2][lane]+ps1[3][lane];
    pS2[(size_t)blockIdx.x*64 + lane] = ps2[0][lane]+ps2[1][lane]+ps2[2][lane]+ps2[3][lane];
  }
}

// ---------------------------------------------------------------------------
// K3b: slow path (expected ~0-50 rows): full f64 scan + 20x extraction.
// Sums go to dedicated k3bS1/k3bS2 via atomics (rare).
// ---------------------------------------------------------------------------
__global__ __launch_bounds__(256) void k3b_slow(
    const float* __restrict__ xT, const double* __restrict__ xxd,
    const unsigned* __restrict__ slowcnt, const unsigned* __restrict__ slowlist,
    const float* __restrict__ uT, const float* __restrict__ vT,
    float* __restrict__ stage, double* __restrict__ k3bS1, double* __restrict__ k3bS2)
{
  __shared__ unsigned long long keyl[4096];
  __shared__ unsigned long long red[4];
  __shared__ unsigned t20[20];
  unsigned nslow = *slowcnt;
  int t = threadIdx.x;
  for (unsigned ii = blockIdx.x; ii < nslow; ii += gridDim.x) {
    int row = (int)slowlist[ii];
    int b = row >> 12, n = row & 4095;
    const float* pn = xT + ((size_t)b*4096 + n)*64;
    double xxn = xxd[(size_t)b*4096 + n];
    for (int m = t; m < 4096; m += 256) {
      const float* pm = xT + ((size_t)b*4096 + m)*64;
      double acc = 0.0;
      #pragma unroll 4
      for (int c = 0; c < 64; c += 4) {
        float4 a  = *(const float4*)(pn + c);
        float4 bf = *(const float4*)(pm + c);
        acc = fma((double)a.x, (double)bf.x, acc);
        acc = fma((double)a.y, (double)bf.y, acc);
        acc = fma((double)a.z, (double)bf.z, acc);
        acc = fma((double)a.w, (double)bf.w, acc);
      }
      double d = fmax(xxn + xxd[(size_t)b*4096 + m] - 2.0*acc, 0.0);
      keyl[m] = (((unsigned long long)__double_as_longlong(d)) & ~0xFFFull)
              | (unsigned long long)m;
    }
    __syncthreads();
    for (int k = 0; k < 20; ++k) {
      unsigned long long mn = ~0ull;
      #pragma unroll
      for (int s = 0; s < 16; ++s) {
        unsigned long long v = keyl[t + s*256];
        mn = (v < mn) ? v : mn;
      }
      for (int off = 32; off > 0; off >>= 1) {
        unsigned long long o = __shfl_down(mn, off);
        mn = (o < mn) ? o : mn;
      }
      if ((t & 63) == 0) red[t >> 6] = mn;
      __syncthreads();
      if (t == 0) {
        unsigned long long w0 = red[0];
        for (int q = 1; q < 4; ++q) w0 = (red[q] < w0) ? red[q] : w0;
        t20[k] = (unsigned)(w0 & 0xFFFull);
        keyl[w0 & 0xFFFull] = ~0ull;
      }
      __syncthreads();
    }
    if (t < 64) {
      const float* ub = uT + (size_t)b*4096*64;
      float mx = -3.4e38f, s1 = 0.f, s2 = 0.f;
      #pragma unroll
      for (int k = 0; k < 20; ++k) {
        unsigned m = t20[k];
        float g = ub[(size_t)m*64 + t];
        mx = fmaxf(mx, g); s1 += g; s2 = fmaf(g, g, s2);
      }
      size_t ro = ((size_t)b*4096 + n)*64 + t;
      float v = vT[ro];
      stage[ro] = mx + v;
      double dv = (double)v;
      __hip_atomic_fetch_add(&k3bS1[b*64 + t], (double)s1 + 20.0*dv,
                             __ATOMIC_RELAXED, __HIP_MEMORY_SCOPE_AGENT);
      __hip_atomic_fetch_add(&k3bS2[b*64 + t], (double)s2 + 2.0*dv*(double)s1 + 20.0*dv*dv,
                             __ATOMIC_RELAXED, __HIP_MEMORY_SCOPE_AGENT);
    }
    __syncthreads();
  }
}

// ---------------------------------------------------------------------------
// K4: reduce partials -> mean/var per (b,o); normalize + leaky-ReLU.
// ---------------------------------------------------------------------------
__global__ __launch_bounds__(256) void k4_final(
    const float* __restrict__ stage,
    const double* __restrict__ pS1, const double* __restrict__ pS2,
    const double* __restrict__ k3bS1, const double* __restrict__ k3bS2,
    float* __restrict__ out)
{
  __shared__ double r1[4], r2[4];
  __shared__ float params[2];
  int bo = blockIdx.x;
  int b = bo >> 6, o = bo & 63;
  int t = threadIdx.x;
  double s1 = 0.0, s2 = 0.0;
  for (int j = t; j < 1024; j += 256) {
    s1 += pS1[(size_t)(b*1024 + j)*64 + o];
    s2 += pS2[(size_t)(b*1024 + j)*64 + o];
  }
  for (int off = 32; off > 0; off >>= 1) {
    s1 += __shfl_down(s1, off);
    s2 += __shfl_down(s2, off);
  }
  if ((t & 63) == 0) { r1[t >> 6] = s1; r2[t >> 6] = s2; }
  __syncthreads();
  if (t == 0) {
    double S1 = r1[0]+r1[1]+r1[2]+r1[3] + k3bS1[bo];
    double S2 = r2[0]+r2[1]+r2[2]+r2[3] + k3bS2[bo];
    double inv = 1.0 / (4096.0 * 20.0);
    double mean = S1 * inv;
    double var  = S2 * inv - mean * mean;
    params[0] = (float)mean;
    params[1] = (float)rsqrt(var + 1e-5);
  }
  __syncthreads();
  float mf = params[0], rs = params[1];
  for (int n = t; n < 4096; n += 256) {
    float y = (stage[((size_t)b*4096 + n)*64 + o] - mf) * rs;
    out[(size_t)bo*4096 + n] = (y >= 0.f) ? y : 0.2f * y;
  }
}

// ---------------------------------------------------------------------------
extern "C" void kernel_launch(void* const* d_in, const int* in_sizes, int n_in,
                              void* d_out, int out_size, void* d_ws, size_t ws_size,
                              hipStream_t stream)
{
  (void)in_sizes; (void)n_in; (void)out_size; (void)ws_size;
  const float* x = (const float*)d_in[0];   // (4,64,4096)
  const float* W = (const float*)d_in[1];   // (64,128)
  float* out = (float*)d_out;

  char* ws = (char*)d_ws;
  size_t off = 0;
  auto alloc = [&](size_t bytes) {
    char* p = ws + off;
    off = (off + bytes + 255) & ~(size_t)255;
    return p;
  };
  float*          uT       = (float*)         alloc((size_t)NROW*64*4);
  float*          vT       = (float*)         alloc((size_t)NROW*64*4);
  float*          xT       = (float*)         alloc((size_t)NROW*64*4);
  float*          stage    = (float*)         alloc((size_t)NROW*64*4);
  unsigned short* xh       = (unsigned short*)alloc((size_t)NROW*64*2);
  unsigned short* xl       = (unsigned short*)alloc((size_t)NROW*64*2);
  float*          xxf      = (float*)         alloc((size_t)NROW*4);
  double*         xxd      = (double*)        alloc((size_t)NROW*8);
  double*         pS1      = (double*)        alloc((size_t)4096*64*8);
  double*         pS2      = (double*)        alloc((size_t)4096*64*8);
  // zeroed region (contiguous): counts, slowcnt, k3bS1, k3bS2
  unsigned*       counts   = (unsigned*)      alloc((size_t)NROW*4);
  unsigned*       slowcnt  = (unsigned*)      alloc(256);
  double*         k3bS1    = (double*)        alloc(256*8);
  double*         k3bS2    = (double*)        alloc(256*8);
  unsigned*       slowlist = (unsigned*)      alloc((size_t)NROW*4);
  unsigned*       surv     = (unsigned*)      alloc((size_t)NROW*CAP*4);

  size_t zbytes = (size_t)NROW*4 + 256 + 2048 + 2048;
  hipMemsetAsync(counts, 0, zbytes, stream);

  k1_prep  <<<256,  256, 0, stream>>>(x, W, xT, xh, xl, xxf, xxd, uT, vT);
  k2_screen<<<512,  256, 0, stream>>>(xh, xl, xxf, counts, surv);
  k3_select<<<4096, 256, 0, stream>>>(xT, xxd, counts, surv, uT, vT,
                                      stage, pS1, pS2, slowcnt, slowlist);
  k3b_slow <<<128,  256, 0, stream>>>(xT, xxd, slowcnt, slowlist,
                                      uT, vT, stage, k3bS1, k3bS2);
  k4_final <<<256,  256, 0, stream>>>(stage, pS1, pS2, k3bS1, k3bS2, out);
}

// Round 3
// 195.628 us; speedup vs baseline: 2.6633x; 1.6874x over previous
//
#include <hip/hip_runtime.h>
#include <hip/hip_bf16.h>
#include <cstdint>
#include <cstddef>

// Problem constants (fixed by reference)
#define BB 4
#define NN 4096
#define NROW (BB*NN)          // 16384 rows
#define SEGW 64               // slots per (row, m-split) segment
#define NSEG 8                // m-splits
#define QPf 27.7f             // push threshold on w_approx (27 + margin)
#define STRICT_KEY (49152u<<12)  // key bound for w_approx < 27.0  ((27+69)*512)
#define DQ 386u               // selection window in q units (>> 2*eps*512)

typedef float v2f   __attribute__((ext_vector_type(2)));
typedef float f32x16 __attribute__((ext_vector_type(16)));
typedef short s16x8 __attribute__((ext_vector_type(8)));
typedef __bf16 bf16x8 __attribute__((ext_vector_type(8)));

__device__ __forceinline__ v2f pkfma(v2f a, v2f b, v2f c) {
  return __builtin_elementwise_fma(a, b, c);
}
__device__ __forceinline__ unsigned short f2bf(float f) {
  unsigned u = __float_as_uint(f);
  u += 0x7FFFu + ((u >> 16) & 1u);      // RNE (no NaN/Inf in data)
  return (unsigned short)(u >> 16);
}
__device__ __forceinline__ float bf2f(unsigned short h) {
  return __uint_as_float(((unsigned)h) << 16);
}

// ---------------------------------------------------------------------------
// K1: prep. xT f32 [point][c]; xh/xl bf16 hi/lo split; xxf/xxd norms;
//     uT = W1.x, vT = (W2-W1).x  [point][o]  (weights in registers)
// ---------------------------------------------------------------------------
__global__ __launch_bounds__(256) void k1_prep(
    const float* __restrict__ x, const float* __restrict__ W,
    float* __restrict__ xT, unsigned short* __restrict__ xh, unsigned short* __restrict__ xl,
    float* __restrict__ xxf, double* __restrict__ xxd,
    float* __restrict__ uT, float* __restrict__ vT)
{
  __shared__ float xc[64][65];   // [c][n]
  __shared__ float xr[64][68];   // [n][c]
  __shared__ float w1[64][65];
  __shared__ float wd[64][65];
  int t = threadIdx.x;
  int b  = blockIdx.x >> 6;
  int n0 = (blockIdx.x & 63) * 64;

  for (int i = t; i < 4096; i += 256) {
    int o = i >> 6, c = i & 63;
    float a = W[o*128 + c];
    w1[o][c] = a;
    wd[o][c] = W[o*128 + 64 + c] - a;
  }
  for (int i = t; i < 4096; i += 256) {
    int c = i >> 6, n = i & 63;
    xc[c][n] = x[((size_t)b*64 + c)*4096 + n0 + n];
  }
  __syncthreads();

  for (int i = t; i < 4096; i += 256) {
    int n = i >> 6, c = i & 63;
    float v = xc[c][n];
    xr[n][c] = v;
    size_t pi = ((size_t)b*4096 + n0 + n)*64 + c;
    xT[pi] = v;
    unsigned short h = f2bf(v);
    float l = v - bf2f(h);
    xh[pi] = h;
    xl[pi] = f2bf(l);
  }
  if (t < 64) {
    int n = t;
    float s0=0,s1=0,s2=0,s3=0; double sd=0.0;
    for (int c = 0; c < 64; c += 4) {
      float a0=xc[c][n],a1=xc[c+1][n],a2=xc[c+2][n],a3=xc[c+3][n];
      s0=fmaf(a0,a0,s0); s1=fmaf(a1,a1,s1); s2=fmaf(a2,a2,s2); s3=fmaf(a3,a3,s3);
      sd += (double)a0*a0 + (double)a1*a1 + (double)a2*a2 + (double)a3*a3;
    }
    xxf[(size_t)b*4096 + n0 + n] = (s0+s1)+(s2+s3);
    xxd[(size_t)b*4096 + n0 + n] = sd;
  }
  v2f w1r[32], wdr[32];
  int o = t & 63;
  #pragma unroll
  for (int j = 0; j < 32; ++j) {
    w1r[j].x = w1[o][2*j]; w1r[j].y = w1[o][2*j+1];
    wdr[j].x = wd[o][2*j]; wdr[j].y = wd[o][2*j+1];
  }
  __syncthreads();

  for (int i = t; i < 4096; i += 256) {
    int n = i >> 6;
    v2f au; au.x=0.f; au.y=0.f;
    v2f av; av.x=0.f; av.y=0.f;
    #pragma unroll
    for (int cb = 0; cb < 16; ++cb) {
      float4 xv = *(const float4*)&xr[n][cb*4];
      v2f p0; p0.x = xv.x; p0.y = xv.y;
      v2f p1; p1.x = xv.z; p1.y = xv.w;
      au = pkfma(w1r[2*cb],   p0, au);
      au = pkfma(w1r[2*cb+1], p1, au);
      av = pkfma(wdr[2*cb],   p0, av);
      av = pkfma(wdr[2*cb+1], p1, av);
    }
    size_t idx = ((size_t)b*4096 + n0 + n)*64 + o;
    uT[idx] = au.x + au.y;
    vT[idx] = av.x + av.y;
  }
}

// ---------------------------------------------------------------------------
// K2: split-bf16 MFMA Gram screen. Grid = 64 n-blocks x 8 m-splits.
// Pushes go to per-(row,ms) private segments via LDS atomics only;
// per-segment counts flushed once at the end with plain stores.
// ---------------------------------------------------------------------------
__global__ __launch_bounds__(256) void k2_screen(
    const unsigned short* __restrict__ xh, const unsigned short* __restrict__ xl,
    const float* __restrict__ xxf,
    unsigned* __restrict__ counts, unsigned* __restrict__ surv)
{
  __shared__ unsigned short mh[2][8192];   // [buf][128 m][64 c], XOR-swizzled
  __shared__ unsigned short ml[2][8192];
  __shared__ unsigned segcnt[256];
  int t  = threadIdx.x;
  int nb = blockIdx.x >> 3;
  int ms = blockIdx.x & 7;
  int row0 = nb * 256;
  int b = row0 >> 12;
  int mbase = ms * 512;
  const unsigned short* xhB = xh + ((size_t)b*4096)*64;
  const unsigned short* xlB = xl + ((size_t)b*4096)*64;

  segcnt[t] = 0u;

  int wv = t >> 6, lane = t & 63;
  int lr = lane & 31, oct = lane >> 5;

  // A-fragments in registers (A,B fed with identical lane->element maps)
  s16x8 ah[2][4], al[2][4];
  #pragma unroll
  for (int nt = 0; nt < 2; ++nt)
    #pragma unroll
    for (int ks = 0; ks < 4; ++ks) {
      size_t rbase = ((size_t)(row0 + wv*64 + nt*32 + lr))*64 + ks*16 + oct*8;
      ah[nt][ks] = *(const s16x8*)(xh + rbase);
      al[nt][ks] = *(const s16x8*)(xl + rbase);
    }

  // stage chunk 0 (LDS write swizzled: byte ^= ((m&7)<<4))
  {
    const char* sH = (const char*)(xhB + (size_t)mbase*64);
    const char* sL = (const char*)(xlB + (size_t)mbase*64);
    #pragma unroll
    for (int it = 0; it < 4; ++it) {
      int j  = it*4096 + t*16;
      int js = j ^ (((j >> 7) & 7) << 4);
      *(float4*)((char*)&mh[0][0] + js) = *(const float4*)(sH + j);
      *(float4*)((char*)&ml[0][0] + js) = *(const float4*)(sL + j);
    }
  }
  __syncthreads();

  for (int ch = 0; ch < 4; ++ch) {
    int cur = ch & 1;
    float4 pH[4], pL[4];
    if (ch < 3) {
      const char* sH = (const char*)(xhB + (size_t)(mbase + (ch+1)*128)*64);
      const char* sL = (const char*)(xlB + (size_t)(mbase + (ch+1)*128)*64);
      #pragma unroll
      for (int it = 0; it < 4; ++it) {
        int j = it*4096 + t*16;
        pH[it] = *(const float4*)(sH + j);
        pL[it] = *(const float4*)(sL + j);
      }
    }
    #pragma unroll
    for (int msub = 0; msub < 4; ++msub) {
      s16x8 bhf[4], blf[4];
      int mloc = msub*32 + lr;
      #pragma unroll
      for (int ks = 0; ks < 4; ++ks) {
        int off  = mloc*128 + ks*32 + oct*16;
        int offs = off ^ ((mloc & 7) << 4);
        bhf[ks] = *(const s16x8*)((const char*)&mh[cur][0] + offs);
        blf[ks] = *(const s16x8*)((const char*)&ml[cur][0] + offs);
      }
      f32x16 a0, a1;
      #pragma unroll
      for (int i = 0; i < 16; ++i) { a0[i] = 0.f; a1[i] = 0.f; }
      #pragma unroll
      for (int ks = 0; ks < 4; ++ks) {
        bf16x8 AH0 = __builtin_bit_cast(bf16x8, ah[0][ks]);
        bf16x8 AH1 = __builtin_bit_cast(bf16x8, ah[1][ks]);
        bf16x8 AL0 = __builtin_bit_cast(bf16x8, al[0][ks]);
        bf16x8 AL1 = __builtin_bit_cast(bf16x8, al[1][ks]);
        bf16x8 BH  = __builtin_bit_cast(bf16x8, bhf[ks]);
        bf16x8 BL  = __builtin_bit_cast(bf16x8, blf[ks]);
        a0 = __builtin_amdgcn_mfma_f32_32x32x16_bf16(AH0, BH, a0, 0, 0, 0);
        a1 = __builtin_amdgcn_mfma_f32_32x32x16_bf16(AH1, BH, a1, 0, 0, 0);
        a0 = __builtin_amdgcn_mfma_f32_32x32x16_bf16(AH0, BL, a0, 0, 0, 0);
        a1 = __builtin_amdgcn_mfma_f32_32x32x16_bf16(AH1, BL, a1, 0, 0, 0);
        a0 = __builtin_amdgcn_mfma_f32_32x32x16_bf16(AL0, BH, a0, 0, 0, 0);
        a1 = __builtin_amdgcn_mfma_f32_32x32x16_bf16(AL1, BH, a1, 0, 0, 0);
      }
      // epilogue: w = xx_m - 2*S ; push via LDS atomics (no global atomics)
      int mg = mbase + ch*128 + msub*32 + lr;
      float xxm = xxf[b*4096 + mg];
      #pragma unroll
      for (int i = 0; i < 16; ++i) {
        int rsub = (i & 3) + 8*(i >> 2) + 4*oct;     // C/D row map (measured)
        float w0 = fmaf(-2.0f, a0[i], xxm);
        if (w0 < QPf) {
          int rloc = wv*64 + rsub;
          int qi = (int)((w0 + 69.0f) * 512.0f);
          qi = min(max(qi, 0), 65535);
          unsigned key = ((unsigned)qi << 12) | (unsigned)mg;
          unsigned slot = atomicAdd(&segcnt[rloc], 1u);
          if (slot < SEGW) surv[(size_t)(row0 + rloc)*(SEGW*NSEG) + ms*SEGW + slot] = key;
        }
        float w1v = fmaf(-2.0f, a1[i], xxm);
        if (w1v < QPf) {
          int rloc = wv*64 + 32 + rsub;
          int qi = (int)((w1v + 69.0f) * 512.0f);
          qi = min(max(qi, 0), 65535);
          unsigned key = ((unsigned)qi << 12) | (unsigned)mg;
          unsigned slot = atomicAdd(&segcnt[rloc], 1u);
          if (slot < SEGW) surv[(size_t)(row0 + rloc)*(SEGW*NSEG) + ms*SEGW + slot] = key;
        }
      }
    }
    if (ch < 3) {
      __syncthreads();
      int nxt = cur ^ 1;
      #pragma unroll
      for (int it = 0; it < 4; ++it) {
        int j  = it*4096 + t*16;
        int js = j ^ (((j >> 7) & 7) << 4);
        *(float4*)((char*)&mh[nxt][0] + js) = pH[it];
        *(float4*)((char*)&ml[nxt][0] + js) = pL[it];
      }
      __syncthreads();
    }
  }
  __syncthreads();
  counts[(size_t)(row0 + t)*NSEG + ms] = segcnt[t];   // unique writer
}

// ---------------------------------------------------------------------------
// K3: per-row wave. 8-segment key load; strict check; 16-iter q-bisection;
// window select (superset of true top-20); f64 rescore; bitonic sort; epilogue.
// ---------------------------------------------------------------------------
__global__ __launch_bounds__(256) void k3_select(
    const float* __restrict__ xT, const double* __restrict__ xxd,
    const unsigned* __restrict__ counts, const unsigned* __restrict__ surv,
    const float* __restrict__ uT, const float* __restrict__ vT,
    float* __restrict__ stage, double* __restrict__ pS1, double* __restrict__ pS2,
    unsigned* __restrict__ slowcnt, unsigned* __restrict__ slowlist)
{
  __shared__ unsigned candm[4][64];
  __shared__ double ps1[4][64], ps2[4][64];
  int wv = threadIdx.x >> 6, lane = threadIdx.x & 63;
  int row = blockIdx.x * 4 + wv;
  int b = row >> 12, n = row & 4095;

  double s1t = 0.0, s2t = 0.0;

  uint4 c0 = *(const uint4*)&counts[(size_t)row*NSEG];
  uint4 c1 = *(const uint4*)&counts[(size_t)row*NSEG + 4];
  unsigned segc[8] = {c0.x, c0.y, c0.z, c0.w, c1.x, c1.y, c1.z, c1.w};
  bool slow = false;
  #pragma unroll
  for (int s = 0; s < 8; ++s) slow = slow || (segc[s] > (unsigned)SEGW);

  unsigned key[8];
  #pragma unroll
  for (int s = 0; s < 8; ++s)
    key[s] = (!slow && lane < (int)segc[s])
           ? surv[(size_t)row*(SEGW*NSEG) + s*SEGW + lane] : 0xFFFFFFFFu;

  int strictc = 0;
  #pragma unroll
  for (int s = 0; s < 8; ++s)
    strictc += __popcll(__ballot(key[s] < STRICT_KEY));
  slow = slow || (strictc < 20);

  int sel = 0;
  if (!slow) {
    // bisect on 16-bit q field: find q20 (q of 20th-smallest key)
    unsigned lo = 0u, hi = 1u << 16;
    for (int it = 0; it < 16; ++it) {
      unsigned mid = (lo + hi) >> 1;
      unsigned Tm = mid << 12;
      int c = 0;
      #pragma unroll
      for (int s = 0; s < 8; ++s)
        c += __popcll(__ballot(key[s] < Tm));
      if (c >= 20) hi = mid; else lo = mid;
    }
    unsigned T = (lo + DQ) << 12;    // window covers q20 + DQ - 1
    int c = 0;
    #pragma unroll
    for (int s = 0; s < 8; ++s)
      c += __popcll(__ballot(key[s] < T));
    sel = c;
    if (sel > 64) {
      slow = true;
    } else {
      int base = 0;
      #pragma unroll
      for (int s = 0; s < 8; ++s) {
        unsigned long long mask = __ballot(key[s] < T);
        if (key[s] < T) {
          int pos = base + __popcll(mask & ((1ull << lane) - 1ull));
          candm[wv][pos] = key[s] & 0xFFFu;
        }
        base += __popcll(mask);
      }
    }
  }

  if (!slow) {
    __builtin_amdgcn_wave_barrier();
    unsigned long long k64 = ~0ull;
    if (lane < sel) {
      int m = (int)candm[wv][lane];
      const float* pn = xT + ((size_t)b*4096 + n)*64;
      const float* pm = xT + ((size_t)b*4096 + m)*64;
      double acc = 0.0;
      #pragma unroll 4
      for (int c2 = 0; c2 < 64; c2 += 4) {
        float4 a  = *(const float4*)(pn + c2);
        float4 bf = *(const float4*)(pm + c2);
        acc = fma((double)a.x, (double)bf.x, acc);
        acc = fma((double)a.y, (double)bf.y, acc);
        acc = fma((double)a.z, (double)bf.z, acc);
        acc = fma((double)a.w, (double)bf.w, acc);
      }
      double d = xxd[(size_t)b*4096 + n] + xxd[(size_t)b*4096 + m] - 2.0*acc;
      d = fmax(d, 0.0);
      k64 = (((unsigned long long)__double_as_longlong(d)) & ~0xFFFull)
          | (unsigned long long)m;            // tie -> lower index (lax.top_k)
    }
    #pragma unroll
    for (int kk = 2; kk <= 64; kk <<= 1) {
      #pragma unroll
      for (int j = kk >> 1; j > 0; j >>= 1) {
        unsigned long long o = __shfl_xor(k64, j);
        bool up    = ((lane & kk) == 0);
        bool lower = ((lane & j) == 0);
        unsigned long long mn = (k64 < o) ? k64 : o;
        unsigned long long mx = (k64 < o) ? o : k64;
        k64 = (lower == up) ? mn : mx;
      }
    }
    int mlow = (int)(k64 & 0xFFFull);          // lanes 0..19 = top-20
    const float* ub = uT + (size_t)b*4096*64;
    float mx = -3.4e38f, s1 = 0.f, s2 = 0.f;
    #pragma unroll
    for (int k = 0; k < 20; ++k) {
      int m = __shfl(mlow, k);
      float g = ub[(size_t)m*64 + lane];
      mx = fmaxf(mx, g); s1 += g; s2 = fmaf(g, g, s2);
    }
    size_t ro = ((size_t)b*4096 + n)*64 + lane;
    float v = vT[ro];
    stage[ro] = mx + v;
    double dv = (double)v;
    s1t = (double)s1 + 20.0*dv;
    s2t = (double)s2 + 2.0*dv*(double)s1 + 20.0*dv*dv;
  } else {
    if (lane == 0) { unsigned i = atomicAdd(slowcnt, 1u); slowlist[i] = row; }
  }

  ps1[wv][lane] = s1t; ps2[wv][lane] = s2t;
  __syncthreads();
  if (wv == 0) {
    pS1[(size_t)blockIdx.x*64 + lane] = ps1[0][lane]+ps1[1][lane]+ps1[2][lane]+ps1[3][lane];
    pS2[(size_t)blockIdx.x*64 + lane] = ps2[0][lane]+ps2[1][lane]+ps2[2][lane]+ps2[3][lane];
  }
}

// ---------------------------------------------------------------------------
// K3b: slow path (expected 0 rows): full f64 scan + 20x extraction.
// ---------------------------------------------------------------------------
__global__ __launch_bounds__(256) void k3b_slow(
    const float* __restrict__ xT, const double* __restrict__ xxd,
    const unsigned* __restrict__ slowcnt, const unsigned* __restrict__ slowlist,
    const float* __restrict__ uT, const float* __restrict__ vT,
    float* __restrict__ stage, double* __restrict__ k3bS1, double* __restrict__ k3bS2)
{
  __shared__ unsigned long long keyl[4096];
  __shared__ unsigned long long red[4];
  __shared__ unsigned t20[20];
  unsigned nslow = *slowcnt;
  int t = threadIdx.x;
  for (unsigned ii = blockIdx.x; ii < nslow; ii += gridDim.x) {
    int row = (int)slowlist[ii];
    int b = row >> 12, n = row & 4095;
    const float* pn = xT + ((size_t)b*4096 + n)*64;
    double xxn = xxd[(size_t)b*4096 + n];
    for (int m = t; m < 4096; m += 256) {
      const float* pm = xT + ((size_t)b*4096 + m)*64;
      double acc = 0.0;
      #pragma unroll 4
      for (int c = 0; c < 64; c += 4) {
        float4 a  = *(const float4*)(pn + c);
        float4 bf = *(const float4*)(pm + c);
        acc = fma((double)a.x, (double)bf.x, acc);
        acc = fma((double)a.y, (double)bf.y, acc);
        acc = fma((double)a.z, (double)bf.z, acc);
        acc = fma((double)a.w, (double)bf.w, acc);
      }
      double d = fmax(xxn + xxd[(size_t)b*4096 + m] - 2.0*acc, 0.0);
      keyl[m] = (((unsigned long long)__double_as_longlong(d)) & ~0xFFFull)
              | (unsigned long long)m;
    }
    __syncthreads();
    for (int k = 0; k < 20; ++k) {
      unsigned long long mn = ~0ull;
      #pragma unroll
      for (int s = 0; s < 16; ++s) {
        unsigned long long v = keyl[t + s*256];
        mn = (v < mn) ? v : mn;
      }
      for (int off = 32; off > 0; off >>= 1) {
        unsigned long long o = __shfl_down(mn, off);
        mn = (o < mn) ? o : mn;
      }
      if ((t & 63) == 0) red[t >> 6] = mn;
      __syncthreads();
      if (t == 0) {
        unsigned long long w0 = red[0];
        for (int q = 1; q < 4; ++q) w0 = (red[q] < w0) ? red[q] : w0;
        t20[k] = (unsigned)(w0 & 0xFFFull);
        keyl[w0 & 0xFFFull] = ~0ull;
      }
      __syncthreads();
    }
    if (t < 64) {
      const float* ub = uT + (size_t)b*4096*64;
      float mx = -3.4e38f, s1 = 0.f, s2 = 0.f;
      #pragma unroll
      for (int k = 0; k < 20; ++k) {
        unsigned m = t20[k];
        float g = ub[(size_t)m*64 + t];
        mx = fmaxf(mx, g); s1 += g; s2 = fmaf(g, g, s2);
      }
      size_t ro = ((size_t)b*4096 + n)*64 + t;
      float v = vT[ro];
      stage[ro] = mx + v;
      double dv = (double)v;
      __hip_atomic_fetch_add(&k3bS1[b*64 + t], (double)s1 + 20.0*dv,
                             __ATOMIC_RELAXED, __HIP_MEMORY_SCOPE_AGENT);
      __hip_atomic_fetch_add(&k3bS2[b*64 + t], (double)s2 + 2.0*dv*(double)s1 + 20.0*dv*dv,
                             __ATOMIC_RELAXED, __HIP_MEMORY_SCOPE_AGENT);
    }
    __syncthreads();
  }
}

// ---------------------------------------------------------------------------
// K4: reduce partials -> mean/var per (b,o); normalize + leaky-ReLU.
// ---------------------------------------------------------------------------
__global__ __launch_bounds__(256) void k4_final(
    const float* __restrict__ stage,
    const double* __restrict__ pS1, const double* __restrict__ pS2,
    const double* __restrict__ k3bS1, const double* __restrict__ k3bS2,
    float* __restrict__ out)
{
  __shared__ double r1[4], r2[4];
  __shared__ float params[2];
  int bo = blockIdx.x;
  int b = bo >> 6, o = bo & 63;
  int t = threadIdx.x;
  double s1 = 0.0, s2 = 0.0;
  for (int j = t; j < 1024; j += 256) {
    s1 += pS1[(size_t)(b*1024 + j)*64 + o];
    s2 += pS2[(size_t)(b*1024 + j)*64 + o];
  }
  for (int off = 32; off > 0; off >>= 1) {
    s1 += __shfl_down(s1, off);
    s2 += __shfl_down(s2, off);
  }
  if ((t & 63) == 0) { r1[t >> 6] = s1; r2[t >> 6] = s2; }
  __syncthreads();
  if (t == 0) {
    double S1 = r1[0]+r1[1]+r1[2]+r1[3] + k3bS1[bo];
    double S2 = r2[0]+r2[1]+r2[2]+r2[3] + k3bS2[bo];
    double inv = 1.0 / (4096.0 * 20.0);
    double mean = S1 * inv;
    double var  = S2 * inv - mean * mean;
    params[0] = (float)mean;
    params[1] = (float)rsqrt(var + 1e-5);
  }
  __syncthreads();
  float mf = params[0], rs = params[1];
  for (int n = t; n < 4096; n += 256) {
    float y = (stage[((size_t)b*4096 + n)*64 + o] - mf) * rs;
    out[(size_t)bo*4096 + n] = (y >= 0.f) ? y : 0.2f * y;
  }
}

// ---------------------------------------------------------------------------
extern "C" void kernel_launch(void* const* d_in, const int* in_sizes, int n_in,
                              void* d_out, int out_size, void* d_ws, size_t ws_size,
                              hipStream_t stream)
{
  (void)in_sizes; (void)n_in; (void)out_size; (void)ws_size;
  const float* x = (const float*)d_in[0];   // (4,64,4096)
  const float* W = (const float*)d_in[1];   // (64,128)
  float* out = (float*)d_out;

  char* ws = (char*)d_ws;
  size_t off = 0;
  auto alloc = [&](size_t bytes) {
    char* p = ws + off;
    off = (off + bytes + 255) & ~(size_t)255;
    return p;
  };
  float*          uT       = (float*)         alloc((size_t)NROW*64*4);
  float*          vT       = (float*)         alloc((size_t)NROW*64*4);
  float*          xT       = (float*)         alloc((size_t)NROW*64*4);
  float*          stage    = (float*)         alloc((size_t)NROW*64*4);
  unsigned short* xh       = (unsigned short*)alloc((size_t)NROW*64*2);
  unsigned short* xl       = (unsigned short*)alloc((size_t)NROW*64*2);
  float*          xxf      = (float*)         alloc((size_t)NROW*4);
  double*         xxd      = (double*)        alloc((size_t)NROW*8);
  double*         pS1      = (double*)        alloc((size_t)4096*64*8);
  double*         pS2      = (double*)        alloc((size_t)4096*64*8);
  unsigned*       counts   = (unsigned*)      alloc((size_t)NROW*NSEG*4);
  // zeroed region (contiguous): slowcnt, k3bS1, k3bS2
  unsigned*       slowcnt  = (unsigned*)      alloc(256);
  double*         k3bS1    = (double*)        alloc(256*8);
  double*         k3bS2    = (double*)        alloc(256*8);
  unsigned*       slowlist = (unsigned*)      alloc((size_t)NROW*4);
  unsigned*       surv     = (unsigned*)      alloc((size_t)NROW*SEGW*NSEG*4);

  hipMemsetAsync(slowcnt, 0, 256 + 2048 + 2048, stream);

  k1_prep  <<<256,  256, 0, stream>>>(x, W, xT, xh, xl, xxf, xxd, uT, vT);
  k2_screen<<<512,  256, 0, stream>>>(xh, xl, xxf, counts, surv);
  k3_select<<<4096, 256, 0, stream>>>(xT, xxd, counts, surv, uT, vT,
                                      stage, pS1, pS2, slowcnt, slowlist);
  k3b_slow <<<128,  256, 0, stream>>>(xT, xxd, slowcnt, slowlist,
                                      uT, vT, stage, k3bS1, k3bS2);
  k4_final <<<256,  256, 0, stream>>>(stage, pS1, pS2, k3bS1, k3bS2, out);
}